// Round 8
// baseline (121.037 us; speedup 1.0000x reference)
//
#include <hip/hip_runtime.h>
#include <math.h>

#define NSEG 20001      // I_DIM + 1 segments / items
#define EMB  128
#define NE   640000

#define SCALE_BLOCKS 313         // ceil(NSEG/64)
#define BOUNDS_BLOCKS 2500       // NE/256 exact
#define LDSL 129                 // padded row stride (floats): 2-way bank aliasing only

__device__ __forceinline__ float dot4(float4 a, float4 b) {
    return a.x*b.x + a.y*b.y + a.z*b.z + a.w*b.w;
}

#define FMA4(acc, s, b) { acc.x += (s)*(b).x; acc.y += (s)*(b).y; acc.z += (s)*(b).z; acc.w += (s)*(b).w; }

__device__ __forceinline__ unsigned f2bf(float x) {
    unsigned u = __float_as_uint(x);
    return (u + 0x7fffu + ((u >> 16) & 1u)) >> 16;   // round-nearest-even
}

// Fused prep (R4-proven):
//  blocks [0, SCALE_BLOCKS): item_scaled(bf16 tab) + a_src/a_dst.
//  blocks [SCALE_BLOCKS, +BOUNDS_BLOCKS): segment bounds.
__global__ __launch_bounds__(256) void prep_kernel(
    const float* __restrict__ emb, const float* __restrict__ W,
    const float* __restrict__ bsc, const float* __restrict__ Watt,
    const int* __restrict__ edge,
    unsigned short* __restrict__ tab,       // bf16 item_scaled, NSEG x EMB
    float* __restrict__ a_src, float* __restrict__ a_dst,
    int* __restrict__ seg_start)
{
    const int tid = threadIdx.x;
    if (blockIdx.x >= SCALE_BLOCKS) {
        // ---- bounds ----
        int e = (blockIdx.x - SCALE_BLOCKS) * 256 + tid;
        int2 p = ((const int2*)edge)[e];            // coalesced 8B
        int sp = __shfl_up(p.x, 1);
        if ((tid & 63) == 0) sp = (e == 0) ? -1 : edge[2*e - 2];
        for (int t = sp + 1; t <= p.x; ++t) seg_start[t] = e;
        if (e == NE - 1) {
            for (int t = p.x + 1; t <= NSEG; ++t) seg_start[t] = NE;
        }
        return;
    }

    // ---- scale branch: 64 rows/block; thread = (cg: 8 cols) x (4 rows) ----
    __shared__ float emb_s[64 * LDSL];   // 33 KB
    const int r0 = blockIdx.x * 64;

    const float4* embg4 = (const float4*)emb;
    const int gmax = NSEG * 32 - 1;
    #pragma unroll
    for (int j = 0; j < 8; ++j) {
        int idx = tid + j * 256;            // 0..2047 tile float4 slots
        int row = idx >> 5, f4 = idx & 31;
        int g = r0 * 32 + idx;
        float4 v = embg4[g <= gmax ? g : gmax];
        float* p = &emb_s[row * LDSL + f4 * 4];
        p[0] = v.x; p[1] = v.y; p[2] = v.z; p[3] = v.w;
    }
    __syncthreads();

    const int cg   = tid & 15;            // cols [8cg, 8cg+8)
    const int rowb = (tid >> 4) * 4;      // 4 rows per thread

    float4 accA[4] = {{0,0,0,0},{0,0,0,0},{0,0,0,0},{0,0,0,0}};
    float4 accB[4] = {{0,0,0,0},{0,0,0,0},{0,0,0,0},{0,0,0,0}};
    const float4* Wg4 = (const float4*)W;

    #pragma unroll 4
    for (int k = 0; k < EMB; ++k) {
        float4 w0 = Wg4[k*32 + cg*2];
        float4 w1 = Wg4[k*32 + cg*2 + 1];
        float a0 = emb_s[(rowb+0)*LDSL + k];
        float a1 = emb_s[(rowb+1)*LDSL + k];
        float a2 = emb_s[(rowb+2)*LDSL + k];
        float a3 = emb_s[(rowb+3)*LDSL + k];
        FMA4(accA[0], a0, w0); FMA4(accB[0], a0, w1);
        FMA4(accA[1], a1, w0); FMA4(accB[1], a1, w1);
        FMA4(accA[2], a2, w0); FMA4(accB[2], a2, w1);
        FMA4(accA[3], a3, w0); FMA4(accB[3], a3, w1);
    }

    const float4 bsA = *(const float4*)&bsc[cg*8];
    const float4 bsB = *(const float4*)&bsc[cg*8 + 4];
    const float4 wsA = *(const float4*)&Watt[cg*8];
    const float4 wsB = *(const float4*)&Watt[cg*8 + 4];
    const float4 wdA = *(const float4*)&Watt[EMB + cg*8];
    const float4 wdB = *(const float4*)&Watt[EMB + cg*8 + 4];

    #pragma unroll
    for (int r = 0; r < 4; ++r) {
        float4 A = accA[r], B = accB[r];
        A.x += bsA.x; A.y += bsA.y; A.z += bsA.z; A.w += bsA.w;
        B.x += bsB.x; B.y += bsB.y; B.z += bsB.z; B.w += bsB.w;
        const int row = r0 + rowb + r;

        if (row < NSEG) {
            uint4 pkt;
            pkt.x = f2bf(A.x) | (f2bf(A.y) << 16);
            pkt.y = f2bf(A.z) | (f2bf(A.w) << 16);
            pkt.z = f2bf(B.x) | (f2bf(B.y) << 16);
            pkt.w = f2bf(B.z) | (f2bf(B.w) << 16);
            ((uint4*)tab)[row * 16 + cg] = pkt;
        }

        float ps = dot4(A, wsA) + dot4(B, wsB);
        float pd = dot4(A, wdA) + dot4(B, wdB);
        #pragma unroll
        for (int off = 8; off >= 1; off >>= 1) {
            ps += __shfl_xor(ps, off);
            pd += __shfl_xor(pd, off);
        }
        if (cg == 0 && row < NSEG) { a_src[row] = ps; a_dst[row] = pd; }
    }
}

// score: per-edge attention score, fully parallel & coalesced.
// pair[e] = { dst<<6 (dword row offset), score (fp32 bits) }
__global__ __launch_bounds__(256) void score_kernel(
    const int* __restrict__ edge, const float* __restrict__ a_src,
    const float* __restrict__ a_dst, const float* __restrict__ b_att,
    int2* __restrict__ pair)
{
    int e = blockIdx.x * 256 + threadIdx.x;       // grid covers NE exactly
    int2 p = ((const int2*)edge)[e];
    float att = a_src[p.x] + a_dst[p.y] + b_att[0];
    att = att > 0.f ? att : 0.2f * att;           // leaky_relu 0.2
    float sc = expf(att - 1.f);
    pair[e] = make_int2(p.y << 6, __float_as_int(sc));
}

__device__ __forceinline__ float bf_lo(unsigned u) { return __uint_as_float(u << 16); }
__device__ __forceinline__ float bf_hi(unsigned u) { return __uint_as_float(u & 0xffff0000u); }

// agg v4: one wave per segment; lane l owns features {2l, 2l+1}.
// Inner loop: all lanes load the SAME pair[j] (broadcast, L1-hit) -> no
// readlane chain, no per-chunk preamble, no exp; ssum needs no reduction
// (every lane accumulates the identical full sum).
__global__ __launch_bounds__(256) void agg_kernel(
    const int2* __restrict__ pair, const int* __restrict__ seg_start,
    const unsigned int* __restrict__ tab32, float* __restrict__ out)
{
    const int wid = blockIdx.x * 4 + (threadIdx.x >> 6);
    if (wid >= NSEG) return;                 // wave-uniform exit
    const int lane = threadIdx.x & 63;
    const unsigned int* tabl = tab32 + lane; // row stride 64 dwords

    const int s0 = seg_start[wid];
    const int s1 = seg_start[wid + 1];

    float accx = 0.f, accy = 0.f;
    float ss0 = 0.f, ss1 = 0.f;

    int j = s0;
    for (; j + 7 < s1; j += 8) {
        int2 p0 = pair[j+0], p1 = pair[j+1], p2 = pair[j+2], p3 = pair[j+3];
        int2 p4 = pair[j+4], p5 = pair[j+5], p6 = pair[j+6], p7 = pair[j+7];
        unsigned u0 = tabl[p0.x], u1 = tabl[p1.x], u2 = tabl[p2.x], u3 = tabl[p3.x];
        unsigned u4 = tabl[p4.x], u5 = tabl[p5.x], u6 = tabl[p6.x], u7 = tabl[p7.x];
        float w0 = __int_as_float(p0.y), w1 = __int_as_float(p1.y);
        float w2 = __int_as_float(p2.y), w3 = __int_as_float(p3.y);
        float w4 = __int_as_float(p4.y), w5 = __int_as_float(p5.y);
        float w6 = __int_as_float(p6.y), w7 = __int_as_float(p7.y);
        ss0 += w0; ss1 += w1; ss0 += w2; ss1 += w3;
        ss0 += w4; ss1 += w5; ss0 += w6; ss1 += w7;
        accx += w0 * bf_lo(u0); accy += w0 * bf_hi(u0);
        accx += w1 * bf_lo(u1); accy += w1 * bf_hi(u1);
        accx += w2 * bf_lo(u2); accy += w2 * bf_hi(u2);
        accx += w3 * bf_lo(u3); accy += w3 * bf_hi(u3);
        accx += w4 * bf_lo(u4); accy += w4 * bf_hi(u4);
        accx += w5 * bf_lo(u5); accy += w5 * bf_hi(u5);
        accx += w6 * bf_lo(u6); accy += w6 * bf_hi(u6);
        accx += w7 * bf_lo(u7); accy += w7 * bf_hi(u7);
    }
    for (; j < s1; ++j) {
        int2 p = pair[j];
        unsigned u = tabl[p.x];
        float w = __int_as_float(p.y);
        ss0 += w;
        accx += w * bf_lo(u);
        accy += w * bf_hi(u);
    }

    float ssum = ss0 + ss1;
    const float inv = (s1 > s0) ? 1.f / ssum : 0.f;
    float ox = accx * inv, oy = accy * inv;
    ox = 1.f / (1.f + expf(-ox));
    oy = 1.f / (1.f + expf(-oy));
    *(float2*)&out[wid * EMB + 2 * lane] = make_float2(ox, oy);
}

extern "C" void kernel_launch(void* const* d_in, const int* in_sizes, int n_in,
                              void* d_out, int out_size, void* d_ws, size_t ws_size,
                              hipStream_t stream) {
    const float* emb  = (const float*)d_in[0];   // (20001, 128)
    const int*   edge = (const int*)  d_in[1];   // (640000, 2)
    const float* W    = (const float*)d_in[2];   // (128, 128)
    const float* bsc  = (const float*)d_in[3];   // (128,)
    const float* Watt = (const float*)d_in[4];   // (256,)
    const float* batt = (const float*)d_in[5];   // (1,)
    float* out = (float*)d_out;                  // (20001, 128)

    unsigned short* tab = (unsigned short*)d_ws;            // NSEG*EMB bf16 (5.12 MB)
    float* a_src = (float*)(tab + (size_t)NSEG * EMB);      // NSEG
    float* a_dst = a_src + NSEG;                            // NSEG
    int*   seg_start = (int*)(a_dst + NSEG);                // NSEG+1
    int2*  pair = (int2*)(seg_start + NSEG + 3);            // NE pairs (8B-aligned)

    prep_kernel<<<SCALE_BLOCKS + BOUNDS_BLOCKS, 256, 0, stream>>>(
        emb, W, bsc, Watt, edge, tab, a_src, a_dst, seg_start);
    score_kernel<<<NE / 256, 256, 0, stream>>>(edge, a_src, a_dst, batt, pair);
    agg_kernel<<<(NSEG + 3) / 4, 256, 0, stream>>>(
        pair, seg_start, (const unsigned int*)tab, out);
}

// Round 9
// 114.585 us; speedup vs baseline: 1.0563x; 1.0563x over previous
//
#include <hip/hip_runtime.h>
#include <math.h>

#define NSEG 20001      // I_DIM + 1 segments / items
#define EMB  128
#define NE   640000

#define SCALE_BLOCKS 313         // ceil(NSEG/64)
#define BOUNDS_BLOCKS 2500       // NE/256 exact
#define LDSL 129                 // padded row stride (floats): 2-way bank aliasing only

__device__ __forceinline__ float dot4(float4 a, float4 b) {
    return a.x*b.x + a.y*b.y + a.z*b.z + a.w*b.w;
}

#define FMA4(acc, s, b) { acc.x += (s)*(b).x; acc.y += (s)*(b).y; acc.z += (s)*(b).z; acc.w += (s)*(b).w; }

__device__ __forceinline__ unsigned q8(float v, float inv) {
    return (unsigned)(__float2int_rn(v * inv)) & 255u;
}

// Fused prep:
//  blocks [0, SCALE_BLOCKS): item_scaled -> int8 rows (tab8) + rscale + a_src/a_dst.
//  blocks [SCALE_BLOCKS, +BOUNDS_BLOCKS): segment bounds + dst compaction.
__global__ __launch_bounds__(256) void prep_kernel(
    const float* __restrict__ emb, const float* __restrict__ W,
    const float* __restrict__ bsc, const float* __restrict__ Watt,
    const int* __restrict__ edge,
    signed char* __restrict__ tab8,         // int8 item_scaled, NSEG x EMB
    float* __restrict__ rscale,             // per-row dequant scale
    float* __restrict__ a_src, float* __restrict__ a_dst,
    int* __restrict__ seg_start, int* __restrict__ dst)
{
    const int tid = threadIdx.x;
    if (blockIdx.x >= SCALE_BLOCKS) {
        // ---- bounds + dst-compaction ----
        int e = (blockIdx.x - SCALE_BLOCKS) * 256 + tid;
        int2 p = ((const int2*)edge)[e];            // coalesced 8B
        dst[e] = p.y;
        int sp = __shfl_up(p.x, 1);
        if ((tid & 63) == 0) sp = (e == 0) ? -1 : edge[2*e - 2];
        for (int t = sp + 1; t <= p.x; ++t) seg_start[t] = e;
        if (e == NE - 1) {
            for (int t = p.x + 1; t <= NSEG; ++t) seg_start[t] = NE;
        }
        return;
    }

    // ---- scale branch: 64 rows/block; thread = (cg: 8 cols) x (4 rows) ----
    __shared__ float emb_s[64 * LDSL];   // 33 KB
    const int r0 = blockIdx.x * 64;

    const float4* embg4 = (const float4*)emb;
    const int gmax = NSEG * 32 - 1;
    #pragma unroll
    for (int j = 0; j < 8; ++j) {
        int idx = tid + j * 256;            // 0..2047 tile float4 slots
        int row = idx >> 5, f4 = idx & 31;
        int g = r0 * 32 + idx;
        float4 v = embg4[g <= gmax ? g : gmax];
        float* p = &emb_s[row * LDSL + f4 * 4];
        p[0] = v.x; p[1] = v.y; p[2] = v.z; p[3] = v.w;
    }
    __syncthreads();

    const int cg   = tid & 15;            // cols [8cg, 8cg+8)
    const int rowb = (tid >> 4) * 4;      // 4 rows per thread

    float4 accA[4] = {{0,0,0,0},{0,0,0,0},{0,0,0,0},{0,0,0,0}};
    float4 accB[4] = {{0,0,0,0},{0,0,0,0},{0,0,0,0},{0,0,0,0}};
    const float4* Wg4 = (const float4*)W;

    #pragma unroll 4
    for (int k = 0; k < EMB; ++k) {
        float4 w0 = Wg4[k*32 + cg*2];
        float4 w1 = Wg4[k*32 + cg*2 + 1];
        float a0 = emb_s[(rowb+0)*LDSL + k];
        float a1 = emb_s[(rowb+1)*LDSL + k];
        float a2 = emb_s[(rowb+2)*LDSL + k];
        float a3 = emb_s[(rowb+3)*LDSL + k];
        FMA4(accA[0], a0, w0); FMA4(accB[0], a0, w1);
        FMA4(accA[1], a1, w0); FMA4(accB[1], a1, w1);
        FMA4(accA[2], a2, w0); FMA4(accB[2], a2, w1);
        FMA4(accA[3], a3, w0); FMA4(accB[3], a3, w1);
    }

    const float4 bsA = *(const float4*)&bsc[cg*8];
    const float4 bsB = *(const float4*)&bsc[cg*8 + 4];
    const float4 wsA = *(const float4*)&Watt[cg*8];
    const float4 wsB = *(const float4*)&Watt[cg*8 + 4];
    const float4 wdA = *(const float4*)&Watt[EMB + cg*8];
    const float4 wdB = *(const float4*)&Watt[EMB + cg*8 + 4];

    #pragma unroll
    for (int r = 0; r < 4; ++r) {
        float4 A = accA[r], B = accB[r];
        A.x += bsA.x; A.y += bsA.y; A.z += bsA.z; A.w += bsA.w;
        B.x += bsB.x; B.y += bsB.y; B.z += bsB.z; B.w += bsB.w;
        const int row = r0 + rowb + r;

        // row absmax over 8 local cols, then over the 16-lane col group
        float m = fmaxf(fmaxf(fmaxf(fabsf(A.x), fabsf(A.y)), fmaxf(fabsf(A.z), fabsf(A.w))),
                        fmaxf(fmaxf(fabsf(B.x), fabsf(B.y)), fmaxf(fabsf(B.z), fabsf(B.w))));
        #pragma unroll
        for (int off = 1; off <= 8; off <<= 1) m = fmaxf(m, __shfl_xor(m, off));
        const float qinv = (m > 0.f) ? 127.f / m : 0.f;

        if (row < NSEG) {
            int2 pkt;
            pkt.x = (int)(q8(A.x,qinv) | (q8(A.y,qinv) << 8) | (q8(A.z,qinv) << 16) | (q8(A.w,qinv) << 24));
            pkt.y = (int)(q8(B.x,qinv) | (q8(B.y,qinv) << 8) | (q8(B.z,qinv) << 16) | (q8(B.w,qinv) << 24));
            ((int2*)tab8)[row * 16 + cg] = pkt;
            if (cg == 0) rscale[row] = m * (1.f / 127.f);
        }

        float ps = dot4(A, wsA) + dot4(B, wsB);
        float pd = dot4(A, wdA) + dot4(B, wdB);
        #pragma unroll
        for (int off = 8; off >= 1; off >>= 1) {
            ps += __shfl_xor(ps, off);
            pd += __shfl_xor(pd, off);
        }
        if (cg == 0 && row < NSEG) { a_src[row] = ps; a_dst[row] = pd; }
    }
}

__device__ __forceinline__ float bcastf(float v, int j) {
    return __uint_as_float(__builtin_amdgcn_readlane(__float_as_uint(v), j));
}

// agg v5: one wave per segment; int8 table (row = 32 dwords, fully L2-resident).
// Lanes pair: sub = lane>>5 picks edge j+sub, dw = lane&31 picks the dword
// (4 int8 features). Per-row scale folded into the broadcast weight.
__global__ __launch_bounds__(256) void agg_kernel(
    const int* __restrict__ dst, const float* __restrict__ a_src,
    const float* __restrict__ a_dst, const float* __restrict__ b_att,
    const float* __restrict__ rscale, const int* __restrict__ seg_start,
    const unsigned int* __restrict__ tab32, float* __restrict__ out)
{
    const int wid = blockIdx.x * 4 + (threadIdx.x >> 6);
    if (wid >= NSEG) return;                 // wave-uniform exit
    const int lane = threadIdx.x & 63;
    const int sub  = lane >> 5;              // edge-in-pair
    const int dw   = lane & 31;              // dword within row
    const unsigned int* tabl = tab32 + dw;   // row stride 32 dwords

    const int s0 = seg_start[wid];
    const int s1 = seg_start[wid + 1];
    const float aS = a_src[wid] + b_att[0];

    float c0=0.f, c1=0.f, c2=0.f, c3=0.f, ssum = 0.f;

    for (int cb = s0; cb < s1; cb += 64) {
        int n = s1 - cb; if (n > 64) n = 64;
        int e = cb + lane;
        int dmine = 0; float sc = 0.f, wsc = 0.f;
        if (lane < n) {
            int d = dst[e];                  // coalesced
            dmine = d << 5;                  // dword row offset
            float att = aS + a_dst[d];
            att = att > 0.f ? att : 0.2f * att;   // leaky_relu 0.2
            sc  = expf(att - 1.f);
            wsc = sc * rscale[d];            // fold dequant scale into weight
        }
        ssum += sc;

        int j = 0;
        // 8 pair-iterations unrolled = 16 edges, 8 outstanding loads
        for (; j + 15 < n; j += 16) {
            #pragma unroll
            for (int p = 0; p < 8; ++p) {
                float wa = bcastf(wsc, j + 2*p);
                float wb = bcastf(wsc, j + 2*p + 1);
                int   da = __builtin_amdgcn_readlane(dmine, j + 2*p);
                int   db = __builtin_amdgcn_readlane(dmine, j + 2*p + 1);
                float w = sub ? wb : wa;
                int   d = sub ? db : da;
                int u = (int)tabl[d];
                c0 += w * (float)((u << 24) >> 24);
                c1 += w * (float)((u << 16) >> 24);
                c2 += w * (float)((u <<  8) >> 24);
                c3 += w * (float)( u        >> 24);
            }
        }
        for (; j < n; j += 2) {
            float wa = bcastf(wsc, j);
            int   da = __builtin_amdgcn_readlane(dmine, j);
            float wb = 0.f; int db = da;
            if (j + 1 < n) {                 // wave-uniform
                wb = bcastf(wsc, j + 1);
                db = __builtin_amdgcn_readlane(dmine, j + 1);
            }
            float w = sub ? wb : wa;
            int   d = sub ? db : da;
            int u = (int)tabl[d];
            c0 += w * (float)((u << 24) >> 24);
            c1 += w * (float)((u << 16) >> 24);
            c2 += w * (float)((u <<  8) >> 24);
            c3 += w * (float)( u        >> 24);
        }
    }

    // segment score sum (each lane held distinct edges' scores)
    #pragma unroll
    for (int off = 32; off >= 1; off >>= 1) ssum += __shfl_xor(ssum, off);

    // combine the two edge-subsets (lanes l and l+32 share 4 features)
    c0 += __shfl_xor(c0, 32);
    c1 += __shfl_xor(c1, 32);
    c2 += __shfl_xor(c2, 32);
    c3 += __shfl_xor(c3, 32);

    const float inv = (s1 > s0) ? 1.f / ssum : 0.f;
    if (lane < 32) {
        float4 o;
        o.x = 1.f / (1.f + expf(-c0 * inv));
        o.y = 1.f / (1.f + expf(-c1 * inv));
        o.z = 1.f / (1.f + expf(-c2 * inv));
        o.w = 1.f / (1.f + expf(-c3 * inv));
        *(float4*)&out[wid * EMB + 4 * dw] = o;
    }
}

extern "C" void kernel_launch(void* const* d_in, const int* in_sizes, int n_in,
                              void* d_out, int out_size, void* d_ws, size_t ws_size,
                              hipStream_t stream) {
    const float* emb  = (const float*)d_in[0];   // (20001, 128)
    const int*   edge = (const int*)  d_in[1];   // (640000, 2)
    const float* W    = (const float*)d_in[2];   // (128, 128)
    const float* bsc  = (const float*)d_in[3];   // (128,)
    const float* Watt = (const float*)d_in[4];   // (256,)
    const float* batt = (const float*)d_in[5];   // (1,)
    float* out = (float*)d_out;                  // (20001, 128)

    signed char* tab8 = (signed char*)d_ws;                 // NSEG*EMB int8 (2.56 MB)
    float* rscale = (float*)(tab8 + (size_t)NSEG * EMB);    // NSEG
    float* a_src = rscale + NSEG;                           // NSEG
    float* a_dst = a_src + NSEG;                            // NSEG
    int*   seg_start = (int*)(a_dst + NSEG);                // NSEG+1
    int*   dstc = seg_start + NSEG + 3;                     // NE (compacted dst col)

    prep_kernel<<<SCALE_BLOCKS + BOUNDS_BLOCKS, 256, 0, stream>>>(
        emb, W, bsc, Watt, edge, tab8, rscale, a_src, a_dst, seg_start, dstc);
    agg_kernel<<<(NSEG + 3) / 4, 256, 0, stream>>>(
        dstc, a_src, a_dst, batt, rscale, seg_start, (const unsigned int*)tab8, out);
}